// Round 1
// baseline (674.508 us; speedup 1.0000x reference)
//
#include <hip/hip_runtime.h>
#include <cmath>

#define NT    8192      // B*N tokens
#define DIM_  1024
#define EXP_  7168
#define CD_   5120      // concat dim (4096 mlp + 1024 attn)
#define OD_   2048

typedef __attribute__((ext_vector_type(8))) short short8;
typedef __attribute__((ext_vector_type(4))) float f32x4;
typedef __attribute__((ext_vector_type(4))) unsigned short ushort4_t;

__device__ __forceinline__ unsigned short f2bf(float f) {
  union { float f; unsigned u; } v; v.f = f;
  return (unsigned short)((v.u + 0x7FFFu + ((v.u >> 16) & 1u)) >> 16);
}
__device__ __forceinline__ float bf2f(unsigned short u) {
  union { unsigned u; float f; } v; v.u = ((unsigned)u) << 16;
  return v.f;
}

#define MFMA16(a, b, c) __builtin_amdgcn_mfma_f32_16x16x32_bf16(a, b, c, 0, 0, 0)

// ---------------- fp32 -> bf16 convert ----------------
__global__ __launch_bounds__(256) void cvt_bf16(const float* __restrict__ in,
                                                unsigned short* __restrict__ out, int n) {
  int i = (blockIdx.x * 256 + threadIdx.x) * 4;
  if (i >= n) return;
  float4 v = *(const float4*)(in + i);
  ushort4_t o;
  o[0] = f2bf(v.x); o[1] = f2bf(v.y); o[2] = f2bf(v.z); o[3] = f2bf(v.w);
  *(ushort4_t*)(out + i) = o;
}

// ---------------- LN1 + expert input mask -> xn bf16 ----------------
__global__ __launch_bounds__(256) void ln1_kernel(const float* __restrict__ x,
    const float* __restrict__ w, const float* __restrict__ b,
    const int* __restrict__ emask, unsigned short* __restrict__ xn) {
  int wave = threadIdx.x >> 6, lane = threadIdx.x & 63;
  int t = blockIdx.x * 4 + wave;
  const float* xt = x + (size_t)t * DIM_;
  float4 v[4];
  float s = 0.f, s2 = 0.f;
#pragma unroll
  for (int i = 0; i < 4; i++) {
    v[i] = *(const float4*)(xt + i * 256 + lane * 4);
    s  += v[i].x + v[i].y + v[i].z + v[i].w;
    s2 += v[i].x * v[i].x + v[i].y * v[i].y + v[i].z * v[i].z + v[i].w * v[i].w;
  }
#pragma unroll
  for (int o = 1; o < 64; o <<= 1) { s += __shfl_xor(s, o); s2 += __shfl_xor(s2, o); }
  float mu = s * (1.f / 1024.f);
  float rs = rsqrtf(s2 * (1.f / 1024.f) - mu * mu + 1e-5f);
  int din = 1024 >> (3 - emask[t]);
  unsigned short* ot = xn + (size_t)t * DIM_;
#pragma unroll
  for (int i = 0; i < 4; i++) {
    int c0 = i * 256 + lane * 4;
    float fv[4] = { v[i].x, v[i].y, v[i].z, v[i].w };
    ushort4_t o;
#pragma unroll
    for (int j = 0; j < 4; j++) {
      int c = c0 + j;
      float val = (c < din) ? (fv[j] - mu) * rs * w[c] + b[c] : 0.f;
      o[j] = f2bf(val);
    }
    *(ushort4_t*)(ot + c0) = o;
  }
}

// ---------------- m97-style 128x128 bf16 GEMM, A(MxK) * W(NxK)^T ----------------
// EPI==1: expand epilogue (q scaled head-major / kv / gelu->concat)
// EPI==2: contract epilogue (+bias -> cy bf16)
template <int EPI>
__global__ __launch_bounds__(256) void gemm_bt(
    const unsigned short* __restrict__ A, const unsigned short* __restrict__ W, int K,
    const float* __restrict__ bias, unsigned short* __restrict__ out0,
    unsigned short* __restrict__ out1, unsigned short* __restrict__ out2) {
  __shared__ unsigned short As[128 * 32];
  __shared__ unsigned short Bs[128 * 32];
  int tid = threadIdx.x;
  int lane = tid & 63;
  int wave = tid >> 6;
  int wm = wave >> 1, wn = wave & 1;
  int lg = lane >> 4, lr = lane & 15;
  int m0 = blockIdx.y * 128, n0 = blockIdx.x * 128;
  f32x4 zf = { 0.f, 0.f, 0.f, 0.f };
  f32x4 acc[4][4];
#pragma unroll
  for (int i = 0; i < 4; i++)
#pragma unroll
    for (int j = 0; j < 4; j++) acc[i][j] = zf;

  for (int kt = 0; kt < K; kt += 32) {
    __syncthreads();
#pragma unroll
    for (int rr = 0; rr < 2; rr++) {
      int idx = rr * 256 + tid;
      int row = idx >> 2;
      int kb = (idx & 3) * 8;
      unsigned ldsoff = (unsigned)((rr * 256 + (wave << 6)) * 16);
      const unsigned short* ga = A + (size_t)(m0 + row) * K + kt + kb;
      const unsigned short* gb = W + (size_t)(n0 + row) * K + kt + kb;
      __builtin_amdgcn_global_load_lds((const __attribute__((address_space(1))) void*)ga,
          (__attribute__((address_space(3))) void*)((char*)As + ldsoff), 16, 0, 0);
      __builtin_amdgcn_global_load_lds((const __attribute__((address_space(1))) void*)gb,
          (__attribute__((address_space(3))) void*)((char*)Bs + ldsoff), 16, 0, 0);
    }
    __syncthreads();
    short8 af[4], bfr[4];
#pragma unroll
    for (int mi = 0; mi < 4; mi++)
      af[mi] = *(const short8*)(As + (wm * 64 + mi * 16 + lr) * 32 + lg * 8);
#pragma unroll
    for (int ni = 0; ni < 4; ni++)
      bfr[ni] = *(const short8*)(Bs + (wn * 64 + ni * 16 + lr) * 32 + lg * 8);
#pragma unroll
    for (int mi = 0; mi < 4; mi++)
#pragma unroll
      for (int ni = 0; ni < 4; ni++)
        acc[mi][ni] = MFMA16(af[mi], bfr[ni], acc[mi][ni]);
  }
  // epilogue: D row = m0+wm*64+mi*16+lg*4+r ; col = n0+wn*64+ni*16+lr
#pragma unroll
  for (int mi = 0; mi < 4; mi++) {
#pragma unroll
    for (int ni = 0; ni < 4; ni++) {
#pragma unroll
      for (int r = 0; r < 4; r++) {
        int grow = m0 + wm * 64 + mi * 16 + lg * 4 + r;
        int gcol = n0 + wn * 64 + ni * 16 + lr;
        float v = acc[mi][ni][r];
        if constexpr (EPI == 1) {
          float bv = bias[gcol & 4095];
          v += (gcol < 4096) ? bv : 0.f;
          if (gcol < 1024) {
            int bb = grow >> 10, n = grow & 1023, h = gcol >> 6, d = gcol & 63;
            out0[(((size_t)(bb * 16 + h) * 1024 + n) << 6) + d] = f2bf(v * 0.125f);
          } else if (gcol < 3072) {
            out1[(size_t)grow * OD_ + (gcol - 1024)] = f2bf(v);
          } else {
            float g = 0.5f * v * (1.f + erff(v * 0.70710678f));
            out2[(size_t)grow * CD_ + (gcol - 3072)] = f2bf(g);
          }
        } else {
          v += bias[gcol];
          out0[(size_t)grow * OD_ + gcol] = f2bf(v);
        }
      }
    }
  }
}

// ---------------- LN2 over 2048 -> k (head-major bf16), v (row-major bf16) ------
__global__ __launch_bounds__(256) void ln2_kernel(const unsigned short* __restrict__ kv,
    const float* __restrict__ w, const float* __restrict__ b,
    unsigned short* __restrict__ kb, unsigned short* __restrict__ vrm) {
  int wave = threadIdx.x >> 6, lane = threadIdx.x & 63;
  int t = blockIdx.x * 4 + wave;
  const unsigned short* p = kv + (size_t)t * OD_;
  float vals[4][8];
  float s = 0.f, s2 = 0.f;
#pragma unroll
  for (int i = 0; i < 4; i++) {
    short8 v = *(const short8*)(p + i * 512 + lane * 8);
#pragma unroll
    for (int j = 0; j < 8; j++) {
      float f = bf2f((unsigned short)v[j]);
      vals[i][j] = f; s += f; s2 += f * f;
    }
  }
#pragma unroll
  for (int o = 1; o < 64; o <<= 1) { s += __shfl_xor(s, o); s2 += __shfl_xor(s2, o); }
  float mu = s * (1.f / 2048.f);
  float rs = rsqrtf(s2 * (1.f / 2048.f) - mu * mu + 1e-5f);
  int bidx = t >> 10, n = t & 1023;
#pragma unroll
  for (int i = 0; i < 4; i++) {
    int c0 = i * 512 + lane * 8;
    short8 o8;
#pragma unroll
    for (int j = 0; j < 8; j++) {
      int c = c0 + j;
      o8[j] = (short)f2bf((vals[i][j] - mu) * rs * w[c] + b[c]);
    }
    if (c0 < 1024) {
      int h = c0 >> 6, d = c0 & 63;
      *(short8*)(kb + (((size_t)(bidx * 16 + h) * 1024 + n) << 6) + d) = o8;
    } else {
      *(short8*)(vrm + (size_t)t * 1024 + (c0 - 1024)) = o8;
    }
  }
}

// ---------------- V transpose: [b,n,h*64+d] -> [b,h,d,n] ----------------
__global__ __launch_bounds__(256) void transpose_v(const unsigned short* __restrict__ vrm,
                                                   unsigned short* __restrict__ vt) {
  int bh = blockIdx.x >> 4;
  int nblk = (blockIdx.x & 15) * 64;
  int b = bh >> 4, h = bh & 15;
  __shared__ unsigned short tile[64][65];
  int tid = threadIdx.x;
  int i = tid >> 2;
  int d0 = (tid & 3) * 16;
  const unsigned short* src = vrm + ((size_t)(b * 1024 + nblk + i)) * 1024 + h * 64 + d0;
  short8 v0 = *(const short8*)(src);
  short8 v1 = *(const short8*)(src + 8);
#pragma unroll
  for (int j = 0; j < 8; j++) {
    tile[d0 + j][i] = (unsigned short)v0[j];
    tile[d0 + 8 + j][i] = (unsigned short)v1[j];
  }
  __syncthreads();
  int d = tid >> 2;
  int i0 = (tid & 3) * 16;
  unsigned short* dst = vt + ((size_t)bh * 64 + d) * 1024 + nblk + i0;
  short8 o0, o1;
#pragma unroll
  for (int j = 0; j < 8; j++) { o0[j] = (short)tile[d][i0 + j]; o1[j] = (short)tile[d][i0 + 8 + j]; }
  *(short8*)dst = o0;
  *(short8*)(dst + 8) = o1;
}

// ---------------- flash attention: 1 wave, 32 q-rows, KV tiles of 32 ----------------
__global__ __launch_bounds__(64) void attn_kernel(const unsigned short* __restrict__ q,
    const unsigned short* __restrict__ k, const unsigned short* __restrict__ vt,
    unsigned short* __restrict__ concat) {
  int bh = blockIdx.x >> 5;
  int q0 = (blockIdx.x & 31) * 32;
  int lane = threadIdx.x;
  int lg = lane >> 4, lr = lane & 15;
  __shared__ unsigned short plds[2][512];
  const unsigned short* qp = q + (size_t)bh * (1024 * 64);
  const unsigned short* kp = k + (size_t)bh * (1024 * 64);
  const unsigned short* vp = vt + (size_t)bh * (64 * 1024);
  short8 qf[2][2];
#pragma unroll
  for (int rb = 0; rb < 2; rb++)
#pragma unroll
    for (int c = 0; c < 2; c++)
      qf[rb][c] = *(const short8*)(qp + (q0 + rb * 16 + lr) * 64 + c * 32 + lg * 8);
  f32x4 zf = { 0.f, 0.f, 0.f, 0.f };
  f32x4 o[2][4];
  float m[2][4], l[2][4];
#pragma unroll
  for (int rb = 0; rb < 2; rb++) {
#pragma unroll
    for (int r = 0; r < 4; r++) { m[rb][r] = -1e30f; l[rb][r] = 0.f; }
#pragma unroll
    for (int nb = 0; nb < 4; nb++) o[rb][nb] = zf;
  }
  for (int kt = 0; kt < 1024; kt += 32) {
    f32x4 s[2][2];
    s[0][0] = zf; s[0][1] = zf; s[1][0] = zf; s[1][1] = zf;
#pragma unroll
    for (int h2 = 0; h2 < 2; h2++) {
      short8 kf0 = *(const short8*)(kp + (kt + h2 * 16 + lr) * 64 + lg * 8);
      short8 kf1 = *(const short8*)(kp + (kt + h2 * 16 + lr) * 64 + 32 + lg * 8);
      s[0][h2] = MFMA16(qf[0][0], kf0, s[0][h2]);
      s[0][h2] = MFMA16(qf[0][1], kf1, s[0][h2]);
      s[1][h2] = MFMA16(qf[1][0], kf0, s[1][h2]);
      s[1][h2] = MFMA16(qf[1][1], kf1, s[1][h2]);
    }
    __syncthreads();  // WAR: previous iteration's P reads complete
#pragma unroll
    for (int rb = 0; rb < 2; rb++) {
      float mx[4], rsum[4];
#pragma unroll
      for (int r = 0; r < 4; r++) mx[r] = fmaxf(s[rb][0][r], s[rb][1][r]);
#pragma unroll
      for (int ofs = 1; ofs < 16; ofs <<= 1)
#pragma unroll
        for (int r = 0; r < 4; r++) mx[r] = fmaxf(mx[r], __shfl_xor(mx[r], ofs));
#pragma unroll
      for (int r = 0; r < 4; r++) {
        float mn = fmaxf(m[rb][r], mx[r]);
        float al = __expf(m[rb][r] - mn);
        float p0 = __expf(s[rb][0][r] - mn);
        float p1 = __expf(s[rb][1][r] - mn);
        m[rb][r] = mn;
        plds[rb][(lg * 4 + r) * 32 + lr] = f2bf(p0);
        plds[rb][(lg * 4 + r) * 32 + 16 + lr] = f2bf(p1);
        rsum[r] = p0 + p1;
        l[rb][r] *= al;
#pragma unroll
        for (int nb = 0; nb < 4; nb++) o[rb][nb][r] *= al;
      }
#pragma unroll
      for (int ofs = 1; ofs < 16; ofs <<= 1)
#pragma unroll
        for (int r = 0; r < 4; r++) rsum[r] += __shfl_xor(rsum[r], ofs);
#pragma unroll
      for (int r = 0; r < 4; r++) l[rb][r] += rsum[r];
    }
    __syncthreads();  // RAW: P visible
    short8 pf0 = *(const short8*)(&plds[0][lr * 32 + lg * 8]);
    short8 pf1 = *(const short8*)(&plds[1][lr * 32 + lg * 8]);
#pragma unroll
    for (int nb = 0; nb < 4; nb++) {
      short8 vf = *(const short8*)(vp + (nb * 16 + lr) * 1024 + kt + lg * 8);
      o[0][nb] = MFMA16(pf0, vf, o[0][nb]);
      o[1][nb] = MFMA16(pf1, vf, o[1][nb]);
    }
  }
  int b = bh >> 4, h = bh & 15;
#pragma unroll
  for (int rb = 0; rb < 2; rb++)
#pragma unroll
    for (int r = 0; r < 4; r++) {
      int n = q0 + rb * 16 + lg * 4 + r;
      size_t t = (size_t)b * 1024 + n;
      float inv = 1.f / l[rb][r];
#pragma unroll
      for (int nb = 0; nb < 4; nb++)
        concat[t * CD_ + 4096 + h * 64 + nb * 16 + lr] = f2bf(o[rb][nb][r] * inv);
    }
}

// ---------------- final epilogue: mask, residual, expert combine ----------------
__global__ __launch_bounds__(256) void final_epi(const unsigned short* __restrict__ cy,
    const float* __restrict__ x, const float* __restrict__ probs,
    const int* __restrict__ emask, float* __restrict__ out) {
  int t = blockIdx.x;
  int c = threadIdx.x * 4;
  int dout = 2048 >> (3 - emask[t]);
  float p = probs[t];
  const unsigned short* cyt = cy + (size_t)t * OD_;
  ushort4_t mv = *(const ushort4_t*)(cyt + c);
  ushort4_t av = *(const ushort4_t*)(cyt + 1024 + c);
  float4 xv = *(const float4*)(x + (size_t)t * 1024 + c);
  float xa[4] = { xv.x, xv.y, xv.z, xv.w };
  float4 o;
  float oa[4];
#pragma unroll
  for (int j = 0; j < 4; j++) {
    float mlp = ((c + j) < dout ? bf2f(mv[j]) : 0.f) + xa[j];
    float att = ((1024 + c + j) < dout ? bf2f(av[j]) : 0.f) + xa[j];
    oa[j] = att + p * mlp;
  }
  o.x = oa[0]; o.y = oa[1]; o.z = oa[2]; o.w = oa[3];
  *(float4*)(out + (size_t)t * 1024 + c) = o;
}

extern "C" void kernel_launch(void* const* d_in, const int* in_sizes, int n_in,
                              void* d_out, int out_size, void* d_ws, size_t ws_size,
                              hipStream_t stream) {
  const float* x        = (const float*)d_in[0];
  const float* probs    = (const float*)d_in[1];
  const float* we       = (const float*)d_in[2];
  const float* mlp_bias = (const float*)d_in[3];
  const float* wc       = (const float*)d_in[4];
  const float* cbias    = (const float*)d_in[5];
  const float* n1w      = (const float*)d_in[6];
  const float* n1b      = (const float*)d_in[7];
  const float* n2w      = (const float*)d_in[8];
  const float* n2b      = (const float*)d_in[9];
  const int*   emask    = (const int*)d_in[10];
  float* out = (float*)d_out;

  char* ws = (char*)d_ws;
  size_t off = 0;
  auto alloc = [&](size_t bytes) {
    char* p = ws + off;
    off += (bytes + 255) & ~(size_t)255;
    return p;
  };
  unsigned short* we_bf = (unsigned short*)alloc((size_t)EXP_ * DIM_ * 2);
  unsigned short* wc_bf = (unsigned short*)alloc((size_t)OD_ * CD_ * 2);
  unsigned short* xn    = (unsigned short*)alloc((size_t)NT * DIM_ * 2);  // reused as vrm
  unsigned short* qb    = (unsigned short*)alloc((size_t)NT * DIM_ * 2);
  unsigned short* kv    = (unsigned short*)alloc((size_t)NT * OD_ * 2);   // reused as cy
  unsigned short* kb    = (unsigned short*)alloc((size_t)NT * DIM_ * 2);
  unsigned short* vt    = (unsigned short*)alloc((size_t)NT * DIM_ * 2);
  unsigned short* cc    = (unsigned short*)alloc((size_t)NT * CD_ * 2);
  unsigned short* vrm = xn;
  unsigned short* cy  = kv;
  if (off > ws_size) return;  // insufficient workspace -> visible failure, no OOB

  cvt_bf16<<<7168, 256, 0, stream>>>(we, we_bf, EXP_ * DIM_);
  cvt_bf16<<<10240, 256, 0, stream>>>(wc, wc_bf, OD_ * CD_);
  ln1_kernel<<<2048, 256, 0, stream>>>(x, n1w, n1b, emask, xn);
  gemm_bt<1><<<dim3(56, 64), 256, 0, stream>>>(xn, we_bf, 1024, mlp_bias, qb, kv, cc);
  ln2_kernel<<<2048, 256, 0, stream>>>(kv, n2w, n2b, kb, vrm);
  transpose_v<<<2048, 256, 0, stream>>>(vrm, vt);
  attn_kernel<<<4096, 64, 0, stream>>>(qb, kb, vt, cc);
  gemm_bt<2><<<dim3(16, 64), 256, 0, stream>>>(cc, wc_bf, 5120, cbias, cy, nullptr, nullptr);
  final_epi<<<8192, 256, 0, stream>>>(cy, x, probs, emask, out);
}

// Round 2
// 552.966 us; speedup vs baseline: 1.2198x; 1.2198x over previous
//
#include <hip/hip_runtime.h>
#include <cmath>

#define NT    8192      // B*N tokens
#define DIM_  1024
#define EXP_  7168
#define CD_   5120      // concat dim (4096 mlp + 1024 attn)
#define OD_   2048

typedef __attribute__((ext_vector_type(8))) short short8;
typedef __attribute__((ext_vector_type(4))) float f32x4;
typedef __attribute__((ext_vector_type(4))) unsigned short ushort4_t;

__device__ __forceinline__ unsigned short f2bf(float f) {
  union { float f; unsigned u; } v; v.f = f;
  return (unsigned short)((v.u + 0x7FFFu + ((v.u >> 16) & 1u)) >> 16);
}
__device__ __forceinline__ float bf2f(unsigned short u) {
  union { unsigned u; float f; } v; v.u = ((unsigned)u) << 16;
  return v.f;
}

#define MFMA16(a, b, c) __builtin_amdgcn_mfma_f32_16x16x32_bf16(a, b, c, 0, 0, 0)

// ---------------- fp32 -> bf16 convert ----------------
__global__ __launch_bounds__(256) void cvt_bf16(const float* __restrict__ in,
                                                unsigned short* __restrict__ out, int n) {
  int i = (blockIdx.x * 256 + threadIdx.x) * 4;
  if (i >= n) return;
  float4 v = *(const float4*)(in + i);
  ushort4_t o;
  o[0] = f2bf(v.x); o[1] = f2bf(v.y); o[2] = f2bf(v.z); o[3] = f2bf(v.w);
  *(ushort4_t*)(out + i) = o;
}

// ---------------- LN1 + expert input mask -> xn bf16 ----------------
__global__ __launch_bounds__(256) void ln1_kernel(const float* __restrict__ x,
    const float* __restrict__ w, const float* __restrict__ b,
    const int* __restrict__ emask, unsigned short* __restrict__ xn) {
  int wave = threadIdx.x >> 6, lane = threadIdx.x & 63;
  int t = blockIdx.x * 4 + wave;
  const float* xt = x + (size_t)t * DIM_;
  float4 v[4];
  float s = 0.f, s2 = 0.f;
#pragma unroll
  for (int i = 0; i < 4; i++) {
    v[i] = *(const float4*)(xt + i * 256 + lane * 4);
    s  += v[i].x + v[i].y + v[i].z + v[i].w;
    s2 += v[i].x * v[i].x + v[i].y * v[i].y + v[i].z * v[i].z + v[i].w * v[i].w;
  }
#pragma unroll
  for (int o = 1; o < 64; o <<= 1) { s += __shfl_xor(s, o); s2 += __shfl_xor(s2, o); }
  float mu = s * (1.f / 1024.f);
  float rs = rsqrtf(s2 * (1.f / 1024.f) - mu * mu + 1e-5f);
  int din = 1024 >> (3 - emask[t]);
  unsigned short* ot = xn + (size_t)t * DIM_;
#pragma unroll
  for (int i = 0; i < 4; i++) {
    int c0 = i * 256 + lane * 4;
    float fv[4] = { v[i].x, v[i].y, v[i].z, v[i].w };
    ushort4_t o;
#pragma unroll
    for (int j = 0; j < 4; j++) {
      int c = c0 + j;
      float val = (c < din) ? (fv[j] - mu) * rs * w[c] + b[c] : 0.f;
      o[j] = f2bf(val);
    }
    *(ushort4_t*)(ot + c0) = o;
  }
}

// ---------------- 256x256 8-phase bf16 GEMM (T1+T2+T3+T4+T5), A(MxK)*W(NxK)^T --
// EPI==1: expand epilogue (q scaled head-major / kv / gelu->concat)
// EPI==2: contract epilogue (+bias -> cy bf16)
template <int EPI, int KK, int NBN>
__global__ __launch_bounds__(512, 2) void gemm8p(
    const unsigned short* __restrict__ A, const unsigned short* __restrict__ W,
    const float* __restrict__ bias, unsigned short* __restrict__ out0,
    unsigned short* __restrict__ out1, unsigned short* __restrict__ out2) {
  extern __shared__ unsigned short lds[];
  unsigned short* As = lds;            // [2][16384] elems (2 x 32 KB)
  unsigned short* Bs = lds + 32768;    // [2][16384]
  const int tid = threadIdx.x;
  const int lane = tid & 63;
  const int wave = tid >> 6;   // 0..7
  const int wm = wave >> 2;    // 0..1
  const int wn = wave & 3;     // 0..3
  const int lg = lane >> 4, lr = lane & 15;
  constexpr int NTILES = KK / 64;

  // T1: bijective XCD swizzle (gridDim.x % 8 == 0 for both shapes)
  int cpx = (int)gridDim.x >> 3;
  int lid = ((int)blockIdx.x & 7) * cpx + ((int)blockIdx.x >> 3);
  int bm = lid / NBN, bn = lid % NBN;
  int m0 = bm * 256, n0 = bn * 256;

  // staging geometry: per seg (64 rows x 64 k), thread tid covers LDS linear
  // slot tid*16B; T2 both-sides swizzle: physical chunk c holds logical chunk
  // c ^ (row&7)  ->  pre-swizzle the GLOBAL k-chunk, keep LDS dest linear.
  const int srow = tid >> 3;                     // row within seg
  const int schunk = (tid & 7) ^ (srow & 7);     // logical 16B k-chunk to fetch

#define STAGE_A(CUR, TA, SEG)                                                        \
  __builtin_amdgcn_global_load_lds(                                                  \
    (const __attribute__((address_space(1))) void*)(A +                              \
      (size_t)(m0 + (SEG) * 64 + srow) * KK + (TA) * 64 + schunk * 8),               \
    (__attribute__((address_space(3))) void*)(As + (CUR) * 16384 + (SEG) * 4096 +    \
      tid * 8), 16, 0, 0)
#define STAGE_B(CUR, TA, SEG)                                                        \
  __builtin_amdgcn_global_load_lds(                                                  \
    (const __attribute__((address_space(1))) void*)(W +                              \
      (size_t)(n0 + (SEG) * 64 + srow) * KK + (TA) * 64 + schunk * 8),               \
    (__attribute__((address_space(3))) void*)(Bs + (CUR) * 16384 + (SEG) * 4096 +    \
      tid * 8), 16, 0, 0)

  short8 afr[4][2], bfr[2][2];
#define LDFRAG_A(CUR, QM)                                                            \
  _Pragma("unroll") for (int mi = 0; mi < 4; mi++)                                   \
  _Pragma("unroll") for (int ks = 0; ks < 2; ks++) {                                 \
    int row_ = wm * 128 + (QM) * 64 + mi * 16 + lr;                                  \
    afr[mi][ks] = *(const short8*)(As + (CUR) * 16384 + row_ * 64 +                  \
                                   (((ks * 4 + lg) ^ (lr & 7)) * 8));                \
  }
#define LDFRAG_B(CUR, QN)                                                            \
  _Pragma("unroll") for (int ni = 0; ni < 2; ni++)                                   \
  _Pragma("unroll") for (int ks = 0; ks < 2; ks++) {                                 \
    int row_ = wn * 64 + (QN) * 32 + ni * 16 + lr;                                   \
    bfr[ni][ks] = *(const short8*)(Bs + (CUR) * 16384 + row_ * 64 +                  \
                                   (((ks * 4 + lg) ^ (lr & 7)) * 8));                \
  }
#define DOMFMA(QM, QN)                                                               \
  __builtin_amdgcn_s_setprio(1);                                                     \
  _Pragma("unroll") for (int mi = 0; mi < 4; mi++)                                   \
  _Pragma("unroll") for (int ni = 0; ni < 2; ni++) {                                 \
    acc[(QM) * 4 + mi][(QN) * 2 + ni] =                                              \
        MFMA16(afr[mi][0], bfr[ni][0], acc[(QM) * 4 + mi][(QN) * 2 + ni]);           \
    acc[(QM) * 4 + mi][(QN) * 2 + ni] =                                              \
        MFMA16(afr[mi][1], bfr[ni][1], acc[(QM) * 4 + mi][(QN) * 2 + ni]);           \
  }                                                                                  \
  __builtin_amdgcn_s_setprio(0);

  // Per K-tile, 4 phases. Stage order for tile t+1 during tile t:
  //   P0: B seg0,seg1 | P1: B seg2,seg3 | P2: A seg0,seg2 | P3: A seg1,seg3
  // Read needs at tile t: P0 {A seg0/2, B all} -> guaranteed by prev vmcnt(2);
  //                       P2 {A seg1/3}        -> guaranteed by P1's vmcnt(4).
#define TILE_BODY(T, CUR) {                                                          \
    const int tn_ = (T) + 1;                                                         \
    const int ta_ = tn_ < NTILES ? tn_ : NTILES - 1;                                 \
    LDFRAG_A(CUR, 0); LDFRAG_B(CUR, 0);                                              \
    STAGE_B((CUR) ^ 1, ta_, 0); STAGE_B((CUR) ^ 1, ta_, 1);                          \
    __builtin_amdgcn_s_barrier();                                                    \
    asm volatile("s_waitcnt lgkmcnt(0)");                                            \
    DOMFMA(0, 0);                                                                    \
    __builtin_amdgcn_s_barrier();                                                    \
    LDFRAG_B(CUR, 1);                                                                \
    STAGE_B((CUR) ^ 1, ta_, 2); STAGE_B((CUR) ^ 1, ta_, 3);                          \
    __builtin_amdgcn_s_barrier();                                                    \
    asm volatile("s_waitcnt lgkmcnt(0)");                                            \
    DOMFMA(0, 1);                                                                    \
    asm volatile("s_waitcnt vmcnt(4)");                                              \
    __builtin_amdgcn_s_barrier();                                                    \
    LDFRAG_A(CUR, 1); LDFRAG_B(CUR, 0);                                              \
    STAGE_A((CUR) ^ 1, ta_, 0); STAGE_A((CUR) ^ 1, ta_, 2);                          \
    __builtin_amdgcn_s_barrier();                                                    \
    asm volatile("s_waitcnt lgkmcnt(0)");                                            \
    DOMFMA(1, 0);                                                                    \
    __builtin_amdgcn_s_barrier();                                                    \
    LDFRAG_B(CUR, 1);                                                                \
    STAGE_A((CUR) ^ 1, ta_, 1); STAGE_A((CUR) ^ 1, ta_, 3);                          \
    __builtin_amdgcn_s_barrier();                                                    \
    asm volatile("s_waitcnt lgkmcnt(0)");                                            \
    DOMFMA(1, 1);                                                                    \
    asm volatile("s_waitcnt vmcnt(2)");                                              \
    __builtin_amdgcn_s_barrier();                                                    \
  }

  f32x4 acc[8][4];
  f32x4 zf = { 0.f, 0.f, 0.f, 0.f };
#pragma unroll
  for (int i = 0; i < 8; i++)
#pragma unroll
    for (int j = 0; j < 4; j++) acc[i][j] = zf;

  // prologue: fully stage tile 0 into buf 0, drain once
  STAGE_B(0, 0, 0); STAGE_B(0, 0, 1); STAGE_B(0, 0, 2); STAGE_B(0, 0, 3);
  STAGE_A(0, 0, 0); STAGE_A(0, 0, 1); STAGE_A(0, 0, 2); STAGE_A(0, 0, 3);
  asm volatile("s_waitcnt vmcnt(0)");
  __builtin_amdgcn_s_barrier();

#pragma unroll 1
  for (int tp = 0; tp < NTILES / 2; ++tp) {
    TILE_BODY(2 * tp, 0)
    TILE_BODY(2 * tp + 1, 1)
  }
  // drain trailing (possibly redundant) stage loads before LDS goes away
  asm volatile("s_waitcnt vmcnt(0)");

  // epilogue: D row = m0 + wm*128 + mi8*16 + lg*4 + r ; col = n0 + wn*64 + nj*16 + lr
#pragma unroll
  for (int mi8 = 0; mi8 < 8; mi8++) {
#pragma unroll
    for (int nj = 0; nj < 4; nj++) {
#pragma unroll
      for (int r = 0; r < 4; r++) {
        int grow = m0 + wm * 128 + mi8 * 16 + lg * 4 + r;
        int gcol = n0 + wn * 64 + nj * 16 + lr;
        float v = acc[mi8][nj][r];
        if constexpr (EPI == 1) {
          float bv = bias[gcol & 4095];
          v += (gcol < 4096) ? bv : 0.f;
          if (gcol < 1024) {
            int bb = grow >> 10, n = grow & 1023, h = gcol >> 6, d = gcol & 63;
            out0[(((size_t)(bb * 16 + h) * 1024 + n) << 6) + d] = f2bf(v * 0.125f);
          } else if (gcol < 3072) {
            out1[(size_t)grow * OD_ + (gcol - 1024)] = f2bf(v);
          } else {
            float g = 0.5f * v * (1.f + erff(v * 0.70710678f));
            out2[(size_t)grow * CD_ + (gcol - 3072)] = f2bf(g);
          }
        } else {
          v += bias[gcol];
          out0[(size_t)grow * OD_ + gcol] = f2bf(v);
        }
      }
    }
  }
#undef STAGE_A
#undef STAGE_B
#undef LDFRAG_A
#undef LDFRAG_B
#undef DOMFMA
#undef TILE_BODY
}

// ---------------- LN2 over 2048 -> k (head-major bf16), v (row-major bf16) ------
__global__ __launch_bounds__(256) void ln2_kernel(const unsigned short* __restrict__ kv,
    const float* __restrict__ w, const float* __restrict__ b,
    unsigned short* __restrict__ kb, unsigned short* __restrict__ vrm) {
  int wave = threadIdx.x >> 6, lane = threadIdx.x & 63;
  int t = blockIdx.x * 4 + wave;
  const unsigned short* p = kv + (size_t)t * OD_;
  float vals[4][8];
  float s = 0.f, s2 = 0.f;
#pragma unroll
  for (int i = 0; i < 4; i++) {
    short8 v = *(const short8*)(p + i * 512 + lane * 8);
#pragma unroll
    for (int j = 0; j < 8; j++) {
      float f = bf2f((unsigned short)v[j]);
      vals[i][j] = f; s += f; s2 += f * f;
    }
  }
#pragma unroll
  for (int o = 1; o < 64; o <<= 1) { s += __shfl_xor(s, o); s2 += __shfl_xor(s2, o); }
  float mu = s * (1.f / 2048.f);
  float rs = rsqrtf(s2 * (1.f / 2048.f) - mu * mu + 1e-5f);
  int bidx = t >> 10, n = t & 1023;
#pragma unroll
  for (int i = 0; i < 4; i++) {
    int c0 = i * 512 + lane * 8;
    short8 o8;
#pragma unroll
    for (int j = 0; j < 8; j++) {
      int c = c0 + j;
      o8[j] = (short)f2bf((vals[i][j] - mu) * rs * w[c] + b[c]);
    }
    if (c0 < 1024) {
      int h = c0 >> 6, d = c0 & 63;
      *(short8*)(kb + (((size_t)(bidx * 16 + h) * 1024 + n) << 6) + d) = o8;
    } else {
      *(short8*)(vrm + (size_t)t * 1024 + (c0 - 1024)) = o8;
    }
  }
}

// ---------------- V transpose: [b,n,h*64+d] -> [b,h,d,n] ----------------
__global__ __launch_bounds__(256) void transpose_v(const unsigned short* __restrict__ vrm,
                                                   unsigned short* __restrict__ vt) {
  int bh = blockIdx.x >> 4;
  int nblk = (blockIdx.x & 15) * 64;
  int b = bh >> 4, h = bh & 15;
  __shared__ unsigned short tile[64][65];
  int tid = threadIdx.x;
  int i = tid >> 2;
  int d0 = (tid & 3) * 16;
  const unsigned short* src = vrm + ((size_t)(b * 1024 + nblk + i)) * 1024 + h * 64 + d0;
  short8 v0 = *(const short8*)(src);
  short8 v1 = *(const short8*)(src + 8);
#pragma unroll
  for (int j = 0; j < 8; j++) {
    tile[d0 + j][i] = (unsigned short)v0[j];
    tile[d0 + 8 + j][i] = (unsigned short)v1[j];
  }
  __syncthreads();
  int d = tid >> 2;
  int i0 = (tid & 3) * 16;
  unsigned short* dst = vt + ((size_t)bh * 64 + d) * 1024 + nblk + i0;
  short8 o0, o1;
#pragma unroll
  for (int j = 0; j < 8; j++) { o0[j] = (short)tile[d][i0 + j]; o1[j] = (short)tile[d][i0 + 8 + j]; }
  *(short8*)dst = o0;
  *(short8*)(dst + 8) = o1;
}

// ---------------- flash attention: 1 wave, 32 q-rows, KV tiles of 32 ----------------
__global__ __launch_bounds__(64) void attn_kernel(const unsigned short* __restrict__ q,
    const unsigned short* __restrict__ k, const unsigned short* __restrict__ vt,
    unsigned short* __restrict__ concat) {
  int bh = blockIdx.x >> 5;
  int q0 = (blockIdx.x & 31) * 32;
  int lane = threadIdx.x;
  int lg = lane >> 4, lr = lane & 15;
  __shared__ unsigned short plds[2][512];
  const unsigned short* qp = q + (size_t)bh * (1024 * 64);
  const unsigned short* kp = k + (size_t)bh * (1024 * 64);
  const unsigned short* vp = vt + (size_t)bh * (64 * 1024);
  short8 qf[2][2];
#pragma unroll
  for (int rb = 0; rb < 2; rb++)
#pragma unroll
    for (int c = 0; c < 2; c++)
      qf[rb][c] = *(const short8*)(qp + (q0 + rb * 16 + lr) * 64 + c * 32 + lg * 8);
  f32x4 zf = { 0.f, 0.f, 0.f, 0.f };
  f32x4 o[2][4];
  float m[2][4], l[2][4];
#pragma unroll
  for (int rb = 0; rb < 2; rb++) {
#pragma unroll
    for (int r = 0; r < 4; r++) { m[rb][r] = -1e30f; l[rb][r] = 0.f; }
#pragma unroll
    for (int nb = 0; nb < 4; nb++) o[rb][nb] = zf;
  }
  for (int kt = 0; kt < 1024; kt += 32) {
    f32x4 s[2][2];
    s[0][0] = zf; s[0][1] = zf; s[1][0] = zf; s[1][1] = zf;
#pragma unroll
    for (int h2 = 0; h2 < 2; h2++) {
      short8 kf0 = *(const short8*)(kp + (kt + h2 * 16 + lr) * 64 + lg * 8);
      short8 kf1 = *(const short8*)(kp + (kt + h2 * 16 + lr) * 64 + 32 + lg * 8);
      s[0][h2] = MFMA16(qf[0][0], kf0, s[0][h2]);
      s[0][h2] = MFMA16(qf[0][1], kf1, s[0][h2]);
      s[1][h2] = MFMA16(qf[1][0], kf0, s[1][h2]);
      s[1][h2] = MFMA16(qf[1][1], kf1, s[1][h2]);
    }
    __syncthreads();  // WAR: previous iteration's P reads complete
#pragma unroll
    for (int rb = 0; rb < 2; rb++) {
      float mx[4], rsum[4];
#pragma unroll
      for (int r = 0; r < 4; r++) mx[r] = fmaxf(s[rb][0][r], s[rb][1][r]);
#pragma unroll
      for (int ofs = 1; ofs < 16; ofs <<= 1)
#pragma unroll
        for (int r = 0; r < 4; r++) mx[r] = fmaxf(mx[r], __shfl_xor(mx[r], ofs));
#pragma unroll
      for (int r = 0; r < 4; r++) {
        float mn = fmaxf(m[rb][r], mx[r]);
        float al = __expf(m[rb][r] - mn);
        float p0 = __expf(s[rb][0][r] - mn);
        float p1 = __expf(s[rb][1][r] - mn);
        m[rb][r] = mn;
        plds[rb][(lg * 4 + r) * 32 + lr] = f2bf(p0);
        plds[rb][(lg * 4 + r) * 32 + 16 + lr] = f2bf(p1);
        rsum[r] = p0 + p1;
        l[rb][r] *= al;
#pragma unroll
        for (int nb = 0; nb < 4; nb++) o[rb][nb][r] *= al;
      }
#pragma unroll
      for (int ofs = 1; ofs < 16; ofs <<= 1)
#pragma unroll
        for (int r = 0; r < 4; r++) rsum[r] += __shfl_xor(rsum[r], ofs);
#pragma unroll
      for (int r = 0; r < 4; r++) l[rb][r] += rsum[r];
    }
    __syncthreads();  // RAW: P visible
    short8 pf0 = *(const short8*)(&plds[0][lr * 32 + lg * 8]);
    short8 pf1 = *(const short8*)(&plds[1][lr * 32 + lg * 8]);
#pragma unroll
    for (int nb = 0; nb < 4; nb++) {
      short8 vf = *(const short8*)(vp + (nb * 16 + lr) * 1024 + kt + lg * 8);
      o[0][nb] = MFMA16(pf0, vf, o[0][nb]);
      o[1][nb] = MFMA16(pf1, vf, o[1][nb]);
    }
  }
  int b = bh >> 4, h = bh & 15;
#pragma unroll
  for (int rb = 0; rb < 2; rb++)
#pragma unroll
    for (int r = 0; r < 4; r++) {
      int n = q0 + rb * 16 + lg * 4 + r;
      size_t t = (size_t)b * 1024 + n;
      float inv = 1.f / l[rb][r];
#pragma unroll
      for (int nb = 0; nb < 4; nb++)
        concat[t * CD_ + 4096 + h * 64 + nb * 16 + lr] = f2bf(o[rb][nb][r] * inv);
    }
}

// ---------------- final epilogue: mask, residual, expert combine ----------------
__global__ __launch_bounds__(256) void final_epi(const unsigned short* __restrict__ cy,
    const float* __restrict__ x, const float* __restrict__ probs,
    const int* __restrict__ emask, float* __restrict__ out) {
  int t = blockIdx.x;
  int c = threadIdx.x * 4;
  int dout = 2048 >> (3 - emask[t]);
  float p = probs[t];
  const unsigned short* cyt = cy + (size_t)t * OD_;
  ushort4_t mv = *(const ushort4_t*)(cyt + c);
  ushort4_t av = *(const ushort4_t*)(cyt + 1024 + c);
  float4 xv = *(const float4*)(x + (size_t)t * 1024 + c);
  float xa[4] = { xv.x, xv.y, xv.z, xv.w };
  float4 o;
  float oa[4];
#pragma unroll
  for (int j = 0; j < 4; j++) {
    float mlp = ((c + j) < dout ? bf2f(mv[j]) : 0.f) + xa[j];
    float att = ((1024 + c + j) < dout ? bf2f(av[j]) : 0.f) + xa[j];
    oa[j] = att + p * mlp;
  }
  o.x = oa[0]; o.y = oa[1]; o.z = oa[2]; o.w = oa[3];
  *(float4*)(out + (size_t)t * 1024 + c) = o;
}

extern "C" void kernel_launch(void* const* d_in, const int* in_sizes, int n_in,
                              void* d_out, int out_size, void* d_ws, size_t ws_size,
                              hipStream_t stream) {
  const float* x        = (const float*)d_in[0];
  const float* probs    = (const float*)d_in[1];
  const float* we       = (const float*)d_in[2];
  const float* mlp_bias = (const float*)d_in[3];
  const float* wc       = (const float*)d_in[4];
  const float* cbias    = (const float*)d_in[5];
  const float* n1w      = (const float*)d_in[6];
  const float* n1b      = (const float*)d_in[7];
  const float* n2w      = (const float*)d_in[8];
  const float* n2b      = (const float*)d_in[9];
  const int*   emask    = (const int*)d_in[10];
  float* out = (float*)d_out;

  char* ws = (char*)d_ws;
  size_t off = 0;
  auto alloc = [&](size_t bytes) {
    char* p = ws + off;
    off += (bytes + 255) & ~(size_t)255;
    return p;
  };
  unsigned short* we_bf = (unsigned short*)alloc((size_t)EXP_ * DIM_ * 2);
  unsigned short* wc_bf = (unsigned short*)alloc((size_t)OD_ * CD_ * 2);
  unsigned short* xn    = (unsigned short*)alloc((size_t)NT * DIM_ * 2);  // reused as vrm
  unsigned short* qb    = (unsigned short*)alloc((size_t)NT * DIM_ * 2);
  unsigned short* kv    = (unsigned short*)alloc((size_t)NT * OD_ * 2);   // reused as cy
  unsigned short* kb    = (unsigned short*)alloc((size_t)NT * DIM_ * 2);
  unsigned short* vt    = (unsigned short*)alloc((size_t)NT * DIM_ * 2);
  unsigned short* cc    = (unsigned short*)alloc((size_t)NT * CD_ * 2);
  unsigned short* vrm = xn;
  unsigned short* cy  = kv;
  if (off > ws_size) return;  // insufficient workspace -> visible failure, no OOB

  // allow 128 KiB dynamic LDS for the 8-phase GEMMs (host-side state, not captured)
  hipFuncSetAttribute((const void*)gemm8p<1, 1024, 28>,
                      hipFuncAttributeMaxDynamicSharedMemorySize, 131072);
  hipFuncSetAttribute((const void*)gemm8p<2, 5120, 8>,
                      hipFuncAttributeMaxDynamicSharedMemorySize, 131072);

  cvt_bf16<<<7168, 256, 0, stream>>>(we, we_bf, EXP_ * DIM_);
  cvt_bf16<<<10240, 256, 0, stream>>>(wc, wc_bf, OD_ * CD_);
  ln1_kernel<<<2048, 256, 0, stream>>>(x, n1w, n1b, emask, xn);
  gemm8p<1, 1024, 28><<<896, 512, 131072, stream>>>(xn, we_bf, mlp_bias, qb, kv, cc);
  ln2_kernel<<<2048, 256, 0, stream>>>(kv, n2w, n2b, kb, vrm);
  transpose_v<<<2048, 256, 0, stream>>>(vrm, vt);
  attn_kernel<<<4096, 64, 0, stream>>>(qb, kb, vt, cc);
  gemm8p<2, 5120, 8><<<256, 512, 131072, stream>>>(cc, wc_bf, cbias, cy, nullptr, nullptr);
  final_epi<<<8192, 256, 0, stream>>>(cy, x, probs, emask, out);
}

// Round 4
// 545.035 us; speedup vs baseline: 1.2375x; 1.0146x over previous
//
#include <hip/hip_runtime.h>
#include <cmath>

#define NT    8192      // B*N tokens
#define DIM_  1024
#define EXP_  7168
#define CD_   5120      // concat dim (4096 mlp + 1024 attn)
#define OD_   2048

typedef __attribute__((ext_vector_type(8))) short short8;
typedef __attribute__((ext_vector_type(4))) float f32x4;
typedef __attribute__((ext_vector_type(4))) unsigned short ushort4_t;

__device__ __forceinline__ unsigned short f2bf(float f) {
  union { float f; unsigned u; } v; v.f = f;
  return (unsigned short)((v.u + 0x7FFFu + ((v.u >> 16) & 1u)) >> 16);
}
__device__ __forceinline__ float bf2f(unsigned short u) {
  union { unsigned u; float f; } v; v.u = ((unsigned)u) << 16;
  return v.f;
}

#define MFMA16(a, b, c) __builtin_amdgcn_mfma_f32_16x16x32_bf16(a, b, c, 0, 0, 0)

// ---------------- fp32 -> bf16 convert ----------------
__global__ __launch_bounds__(256) void cvt_bf16(const float* __restrict__ in,
                                                unsigned short* __restrict__ out, int n) {
  int i = (blockIdx.x * 256 + threadIdx.x) * 4;
  if (i >= n) return;
  float4 v = *(const float4*)(in + i);
  ushort4_t o;
  o[0] = f2bf(v.x); o[1] = f2bf(v.y); o[2] = f2bf(v.z); o[3] = f2bf(v.w);
  *(ushort4_t*)(out + i) = o;
}

// ---------------- LN1 + expert input mask -> xn bf16 ----------------
__global__ __launch_bounds__(256) void ln1_kernel(const float* __restrict__ x,
    const float* __restrict__ w, const float* __restrict__ b,
    const int* __restrict__ emask, unsigned short* __restrict__ xn) {
  int wave = threadIdx.x >> 6, lane = threadIdx.x & 63;
  int t = blockIdx.x * 4 + wave;
  const float* xt = x + (size_t)t * DIM_;
  float4 v[4];
  float s = 0.f, s2 = 0.f;
#pragma unroll
  for (int i = 0; i < 4; i++) {
    v[i] = *(const float4*)(xt + i * 256 + lane * 4);
    s  += v[i].x + v[i].y + v[i].z + v[i].w;
    s2 += v[i].x * v[i].x + v[i].y * v[i].y + v[i].z * v[i].z + v[i].w * v[i].w;
  }
#pragma unroll
  for (int o = 1; o < 64; o <<= 1) { s += __shfl_xor(s, o); s2 += __shfl_xor(s2, o); }
  float mu = s * (1.f / 1024.f);
  float rs = rsqrtf(s2 * (1.f / 1024.f) - mu * mu + 1e-5f);
  int din = 1024 >> (3 - emask[t]);
  unsigned short* ot = xn + (size_t)t * DIM_;
#pragma unroll
  for (int i = 0; i < 4; i++) {
    int c0 = i * 256 + lane * 4;
    float fv[4] = { v[i].x, v[i].y, v[i].z, v[i].w };
    ushort4_t o;
#pragma unroll
    for (int j = 0; j < 4; j++) {
      int c = c0 + j;
      float val = (c < din) ? (fv[j] - mu) * rs * w[c] + b[c] : 0.f;
      o[j] = f2bf(val);
    }
    *(ushort4_t*)(ot + c0) = o;
  }
}

// ---------------- 256x256 8-phase bf16 GEMM, deep-prefetch schedule ----------
// Wave wm owns A rows {wm*64..} (QM=0) and {128+wm*64..} (QM=1): QM selects A-half.
// Wave wn owns B rows {wn*32..} (QN=0) and {128+wn*32..} (QN=1): QN selects B-half.
// Per tile t (slot c=t&1): P0 reads A0,B0 | P1 reads B1 | P2 reads A1 | P3 regs only.
// Stage: P0: B1(t+1)->c^1 | P1: A1(t+1)->c^1 | P2: A0(t+2)->c | P3: B0(t+2)->c
//   (A0/B0 regions of slot c are dead after P0). Waits: vmcnt(6)@P0-end (frees
//   B1(t),A1(t); 3-4 phase cover), vmcnt(8)@P3-end (frees A0,B0(t+1); 4-5 phases).
// EPI==1: expand epilogue (q scaled head-major / kv / gelu->concat)
// EPI==2: contract epilogue (+bias -> cy bf16)
template <int EPI, int KK, int NBN>
__global__ __launch_bounds__(512, 2) void gemm8p(
    const unsigned short* __restrict__ A, const unsigned short* __restrict__ W,
    const float* __restrict__ bias, unsigned short* __restrict__ out0,
    unsigned short* __restrict__ out1, unsigned short* __restrict__ out2) {
  extern __shared__ unsigned short lds[];
  unsigned short* As = lds;            // [2 slots][16384] elems (2 x 32 KB)
  unsigned short* Bs = lds + 32768;    // [2 slots][16384]
  const int tid = threadIdx.x;
  const int lane = tid & 63;
  const int wave = tid >> 6;   // 0..7
  const int wm = wave >> 2;    // 0..1
  const int wn = wave & 3;     // 0..3
  const int lg = lane >> 4, lr = lane & 15;
  constexpr int NTILES = KK / 64;

  // T1: bijective XCD swizzle (gridDim.x % 8 == 0 for both shapes)
  int cpx = (int)gridDim.x >> 3;
  int lid = ((int)blockIdx.x & 7) * cpx + ((int)blockIdx.x >> 3);
  int bm = lid / NBN, bn = lid % NBN;
  int m0 = bm * 256, n0 = bn * 256;

  // staging: seg = 64 rows x 64 k (8 KB); thread tid -> LDS slot tid*16B (linear),
  // T2 swizzle via pre-swizzled GLOBAL chunk: phys chunk (tid&7) holds logical
  // chunk (tid&7)^(row&7).
  const int srow = tid >> 3;
  const int schunk = (tid & 7) ^ (srow & 7);

#define STAGE_A(TT, SEG)                                                             \
  __builtin_amdgcn_global_load_lds(                                                  \
    (const __attribute__((address_space(1))) void*)(A +                              \
      (size_t)(m0 + (SEG) * 64 + srow) * KK + (TT) * 64 + schunk * 8),               \
    (__attribute__((address_space(3))) void*)(As + ((TT) & 1) * 16384 +              \
      (SEG) * 4096 + tid * 8), 16, 0, 0)
#define STAGE_B(TT, SEG)                                                             \
  __builtin_amdgcn_global_load_lds(                                                  \
    (const __attribute__((address_space(1))) void*)(W +                              \
      (size_t)(n0 + (SEG) * 64 + srow) * KK + (TT) * 64 + schunk * 8),               \
    (__attribute__((address_space(3))) void*)(Bs + ((TT) & 1) * 16384 +              \
      (SEG) * 4096 + tid * 8), 16, 0, 0)

  short8 afr[4][2], bfr[2][2][2];
#define LDFRAG_A(C, QM)                                                              \
  _Pragma("unroll") for (int mi = 0; mi < 4; mi++)                                   \
  _Pragma("unroll") for (int ks = 0; ks < 2; ks++) {                                 \
    int row_ = wm * 64 + (QM) * 128 + mi * 16 + lr;                                  \
    afr[mi][ks] = *(const short8*)(As + (C) * 16384 + row_ * 64 +                    \
                                   (((ks * 4 + lg) ^ (lr & 7)) * 8));                \
  }
#define LDFRAG_B(C, QN)                                                              \
  _Pragma("unroll") for (int ni = 0; ni < 2; ni++)                                   \
  _Pragma("unroll") for (int ks = 0; ks < 2; ks++) {                                 \
    int row_ = wn * 32 + (QN) * 128 + ni * 16 + lr;                                  \
    bfr[QN][ni][ks] = *(const short8*)(Bs + (C) * 16384 + row_ * 64 +                \
                                       (((ks * 4 + lg) ^ (lr & 7)) * 8));            \
  }
#define DOMFMA(QM, QN)                                                               \
  __builtin_amdgcn_s_setprio(1);                                                     \
  _Pragma("unroll") for (int mi = 0; mi < 4; mi++)                                   \
  _Pragma("unroll") for (int ni = 0; ni < 2; ni++) {                                 \
    acc[(QM) * 4 + mi][(QN) * 2 + ni] =                                              \
        MFMA16(afr[mi][0], bfr[QN][ni][0], acc[(QM) * 4 + mi][(QN) * 2 + ni]);       \
    acc[(QM) * 4 + mi][(QN) * 2 + ni] =                                              \
        MFMA16(afr[mi][1], bfr[QN][ni][1], acc[(QM) * 4 + mi][(QN) * 2 + ni]);       \
  }                                                                                  \
  __builtin_amdgcn_s_setprio(0);

#define TILE_BODY(T, C) {                                                            \
    const int tn1 = ((T) + 1 < NTILES) ? (T) + 1 : NTILES - 1;                       \
    const int tn2 = ((T) + 2 < NTILES) ? (T) + 2 : NTILES - 1;                       \
    /* P0 */                                                                         \
    LDFRAG_A(C, 0); LDFRAG_B(C, 0);                                                  \
    STAGE_B(tn1, 2); STAGE_B(tn1, 3);                                                \
    __builtin_amdgcn_s_barrier();                                                    \
    asm volatile("s_waitcnt lgkmcnt(0)");                                            \
    DOMFMA(0, 0);                                                                    \
    asm volatile("s_waitcnt vmcnt(6)" ::: "memory");                                 \
    __builtin_amdgcn_s_barrier();                                                    \
    /* P1 */                                                                         \
    LDFRAG_B(C, 1);                                                                  \
    STAGE_A(tn1, 2); STAGE_A(tn1, 3);                                                \
    __builtin_amdgcn_s_barrier();                                                    \
    asm volatile("s_waitcnt lgkmcnt(0)");                                            \
    DOMFMA(0, 1);                                                                    \
    __builtin_amdgcn_s_barrier();                                                    \
    /* P2 */                                                                         \
    LDFRAG_A(C, 1);                                                                  \
    STAGE_A(tn2, 0); STAGE_A(tn2, 1);                                                \
    __builtin_amdgcn_s_barrier();                                                    \
    asm volatile("s_waitcnt lgkmcnt(0)");                                            \
    DOMFMA(1, 0);                                                                    \
    __builtin_amdgcn_s_barrier();                                                    \
    /* P3 (B quad 1 still in regs) */                                                \
    STAGE_B(tn2, 0); STAGE_B(tn2, 1);                                                \
    __builtin_amdgcn_s_barrier();                                                    \
    DOMFMA(1, 1);                                                                    \
    asm volatile("s_waitcnt vmcnt(8)" ::: "memory");                                 \
    __builtin_amdgcn_s_barrier();                                                    \
  }

  f32x4 acc[8][4];
  f32x4 zf = { 0.f, 0.f, 0.f, 0.f };
#pragma unroll
  for (int i = 0; i < 8; i++)
#pragma unroll
    for (int j = 0; j < 4; j++) acc[i][j] = zf;

  // prologue: tile0 fully (8 loads) then A0(1),B0(1) (4 loads); wait tile0 only
  STAGE_A(0, 0); STAGE_A(0, 1); STAGE_A(0, 2); STAGE_A(0, 3);
  STAGE_B(0, 0); STAGE_B(0, 1); STAGE_B(0, 2); STAGE_B(0, 3);
  STAGE_A(1, 0); STAGE_A(1, 1);
  STAGE_B(1, 0); STAGE_B(1, 1);
  asm volatile("s_waitcnt vmcnt(4)" ::: "memory");
  __builtin_amdgcn_s_barrier();

#pragma unroll 1
  for (int tp = 0; tp < NTILES / 2; ++tp) {
    TILE_BODY(2 * tp, 0)
    TILE_BODY(2 * tp + 1, 1)
  }
  // drain trailing stage loads before LDS goes away
  asm volatile("s_waitcnt vmcnt(0)" ::: "memory");

  // epilogue: grow = m0 + wm*64 + QM*128 + mi*16 + lg*4 + r,  QM=mi8>>2, mi=mi8&3
  //           gcol = n0 + wn*32 + QN*128 + ni*16 + lr,        QN=nj>>1,  ni=nj&1
#pragma unroll
  for (int mi8 = 0; mi8 < 8; mi8++) {
#pragma unroll
    for (int nj = 0; nj < 4; nj++) {
#pragma unroll
      for (int r = 0; r < 4; r++) {
        int grow = m0 + wm * 64 + (mi8 >> 2) * 128 + (mi8 & 3) * 16 + lg * 4 + r;
        int gcol = n0 + wn * 32 + (nj >> 1) * 128 + (nj & 1) * 16 + lr;
        float v = acc[mi8][nj][r];
        if constexpr (EPI == 1) {
          float bv = bias[gcol & 4095];
          v += (gcol < 4096) ? bv : 0.f;
          if (gcol < 1024) {
            int bb = grow >> 10, n = grow & 1023, h = gcol >> 6, d = gcol & 63;
            out0[(((size_t)(bb * 16 + h) * 1024 + n) << 6) + d] = f2bf(v * 0.125f);
          } else if (gcol < 3072) {
            out1[(size_t)grow * OD_ + (gcol - 1024)] = f2bf(v);
          } else {
            float g = 0.5f * v * (1.f + erff(v * 0.70710678f));
            out2[(size_t)grow * CD_ + (gcol - 3072)] = f2bf(g);
          }
        } else {
          v += bias[gcol];
          out0[(size_t)grow * OD_ + gcol] = f2bf(v);
        }
      }
    }
  }
#undef STAGE_A
#undef STAGE_B
#undef LDFRAG_A
#undef LDFRAG_B
#undef DOMFMA
#undef TILE_BODY
}

// ---------------- LN2 over 2048 -> k (head-major bf16), v (row-major bf16) ------
__global__ __launch_bounds__(256) void ln2_kernel(const unsigned short* __restrict__ kv,
    const float* __restrict__ w, const float* __restrict__ b,
    unsigned short* __restrict__ kb, unsigned short* __restrict__ vrm) {
  int wave = threadIdx.x >> 6, lane = threadIdx.x & 63;
  int t = blockIdx.x * 4 + wave;
  const unsigned short* p = kv + (size_t)t * OD_;
  float vals[4][8];
  float s = 0.f, s2 = 0.f;
#pragma unroll
  for (int i = 0; i < 4; i++) {
    short8 v = *(const short8*)(p + i * 512 + lane * 8);
#pragma unroll
    for (int j = 0; j < 8; j++) {
      float f = bf2f((unsigned short)v[j]);
      vals[i][j] = f; s += f; s2 += f * f;
    }
  }
#pragma unroll
  for (int o = 1; o < 64; o <<= 1) { s += __shfl_xor(s, o); s2 += __shfl_xor(s2, o); }
  float mu = s * (1.f / 2048.f);
  float rs = rsqrtf(s2 * (1.f / 2048.f) - mu * mu + 1e-5f);
  int bidx = t >> 10, n = t & 1023;
#pragma unroll
  for (int i = 0; i < 4; i++) {
    int c0 = i * 512 + lane * 8;
    short8 o8;
#pragma unroll
    for (int j = 0; j < 8; j++) {
      int c = c0 + j;
      o8[j] = (short)f2bf((vals[i][j] - mu) * rs * w[c] + b[c]);
    }
    if (c0 < 1024) {
      int h = c0 >> 6, d = c0 & 63;
      *(short8*)(kb + (((size_t)(bidx * 16 + h) * 1024 + n) << 6) + d) = o8;
    } else {
      *(short8*)(vrm + (size_t)t * 1024 + (c0 - 1024)) = o8;
    }
  }
}

// ---------------- V transpose: [b,n,h*64+d] -> [b,h,d,n] ----------------
__global__ __launch_bounds__(256) void transpose_v(const unsigned short* __restrict__ vrm,
                                                   unsigned short* __restrict__ vt) {
  int bh = blockIdx.x >> 4;
  int nblk = (blockIdx.x & 15) * 64;
  int b = bh >> 4, h = bh & 15;
  __shared__ unsigned short tile[64][65];
  int tid = threadIdx.x;
  int i = tid >> 2;
  int d0 = (tid & 3) * 16;
  const unsigned short* src = vrm + ((size_t)(b * 1024 + nblk + i)) * 1024 + h * 64 + d0;
  short8 v0 = *(const short8*)(src);
  short8 v1 = *(const short8*)(src + 8);
#pragma unroll
  for (int j = 0; j < 8; j++) {
    tile[d0 + j][i] = (unsigned short)v0[j];
    tile[d0 + 8 + j][i] = (unsigned short)v1[j];
  }
  __syncthreads();
  int d = tid >> 2;
  int i0 = (tid & 3) * 16;
  unsigned short* dst = vt + ((size_t)bh * 64 + d) * 1024 + nblk + i0;
  short8 o0, o1;
#pragma unroll
  for (int j = 0; j < 8; j++) { o0[j] = (short)tile[d][i0 + j]; o1[j] = (short)tile[d][i0 + 8 + j]; }
  *(short8*)dst = o0;
  *(short8*)(dst + 8) = o1;
}

// ---------------- flash attention: 1 wave, 32 q-rows, KV tiles of 32 ----------------
__global__ __launch_bounds__(64) void attn_kernel(const unsigned short* __restrict__ q,
    const unsigned short* __restrict__ k, const unsigned short* __restrict__ vt,
    unsigned short* __restrict__ concat) {
  int bh = blockIdx.x >> 5;
  int q0 = (blockIdx.x & 31) * 32;
  int lane = threadIdx.x;
  int lg = lane >> 4, lr = lane & 15;
  __shared__ unsigned short plds[2][512];
  const unsigned short* qp = q + (size_t)bh * (1024 * 64);
  const unsigned short* kp = k + (size_t)bh * (1024 * 64);
  const unsigned short* vp = vt + (size_t)bh * (64 * 1024);
  short8 qf[2][2];
#pragma unroll
  for (int rb = 0; rb < 2; rb++)
#pragma unroll
    for (int c = 0; c < 2; c++)
      qf[rb][c] = *(const short8*)(qp + (q0 + rb * 16 + lr) * 64 + c * 32 + lg * 8);
  f32x4 zf = { 0.f, 0.f, 0.f, 0.f };
  f32x4 o[2][4];
  float m[2][4], l[2][4];
#pragma unroll
  for (int rb = 0; rb < 2; rb++) {
#pragma unroll
    for (int r = 0; r < 4; r++) { m[rb][r] = -1e30f; l[rb][r] = 0.f; }
#pragma unroll
    for (int nb = 0; nb < 4; nb++) o[rb][nb] = zf;
  }
  for (int kt = 0; kt < 1024; kt += 32) {
    f32x4 s[2][2];
    s[0][0] = zf; s[0][1] = zf; s[1][0] = zf; s[1][1] = zf;
#pragma unroll
    for (int h2 = 0; h2 < 2; h2++) {
      short8 kf0 = *(const short8*)(kp + (kt + h2 * 16 + lr) * 64 + lg * 8);
      short8 kf1 = *(const short8*)(kp + (kt + h2 * 16 + lr) * 64 + 32 + lg * 8);
      s[0][h2] = MFMA16(qf[0][0], kf0, s[0][h2]);
      s[0][h2] = MFMA16(qf[0][1], kf1, s[0][h2]);
      s[1][h2] = MFMA16(qf[1][0], kf0, s[1][h2]);
      s[1][h2] = MFMA16(qf[1][1], kf1, s[1][h2]);
    }
    __syncthreads();  // WAR: previous iteration's P reads complete
#pragma unroll
    for (int rb = 0; rb < 2; rb++) {
      float mx[4], rsum[4];
#pragma unroll
      for (int r = 0; r < 4; r++) mx[r] = fmaxf(s[rb][0][r], s[rb][1][r]);
#pragma unroll
      for (int ofs = 1; ofs < 16; ofs <<= 1)
#pragma unroll
        for (int r = 0; r < 4; r++) mx[r] = fmaxf(mx[r], __shfl_xor(mx[r], ofs));
#pragma unroll
      for (int r = 0; r < 4; r++) {
        float mn = fmaxf(m[rb][r], mx[r]);
        float al = __expf(m[rb][r] - mn);
        float p0 = __expf(s[rb][0][r] - mn);
        float p1 = __expf(s[rb][1][r] - mn);
        m[rb][r] = mn;
        plds[rb][(lg * 4 + r) * 32 + lr] = f2bf(p0);
        plds[rb][(lg * 4 + r) * 32 + 16 + lr] = f2bf(p1);
        rsum[r] = p0 + p1;
        l[rb][r] *= al;
#pragma unroll
        for (int nb = 0; nb < 4; nb++) o[rb][nb][r] *= al;
      }
#pragma unroll
      for (int ofs = 1; ofs < 16; ofs <<= 1)
#pragma unroll
        for (int r = 0; r < 4; r++) rsum[r] += __shfl_xor(rsum[r], ofs);
#pragma unroll
      for (int r = 0; r < 4; r++) l[rb][r] += rsum[r];
    }
    __syncthreads();  // RAW: P visible
    short8 pf0 = *(const short8*)(&plds[0][lr * 32 + lg * 8]);
    short8 pf1 = *(const short8*)(&plds[1][lr * 32 + lg * 8]);
#pragma unroll
    for (int nb = 0; nb < 4; nb++) {
      short8 vf = *(const short8*)(vp + (nb * 16 + lr) * 1024 + kt + lg * 8);
      o[0][nb] = MFMA16(pf0, vf, o[0][nb]);
      o[1][nb] = MFMA16(pf1, vf, o[1][nb]);
    }
  }
  int b = bh >> 4, h = bh & 15;
#pragma unroll
  for (int rb = 0; rb < 2; rb++)
#pragma unroll
    for (int r = 0; r < 4; r++) {
      int n = q0 + rb * 16 + lg * 4 + r;
      size_t t = (size_t)b * 1024 + n;
      float inv = 1.f / l[rb][r];
#pragma unroll
      for (int nb = 0; nb < 4; nb++)
        concat[t * CD_ + 4096 + h * 64 + nb * 16 + lr] = f2bf(o[rb][nb][r] * inv);
    }
}

// ---------------- final epilogue: mask, residual, expert combine ----------------
__global__ __launch_bounds__(256) void final_epi(const unsigned short* __restrict__ cy,
    const float* __restrict__ x, const float* __restrict__ probs,
    const int* __restrict__ emask, float* __restrict__ out) {
  int t = blockIdx.x;
  int c = threadIdx.x * 4;
  int dout = 2048 >> (3 - emask[t]);
  float p = probs[t];
  const unsigned short* cyt = cy + (size_t)t * OD_;
  ushort4_t mv = *(const ushort4_t*)(cyt + c);
  ushort4_t av = *(const ushort4_t*)(cyt + 1024 + c);
  float4 xv = *(const float4*)(x + (size_t)t * 1024 + c);
  float xa[4] = { xv.x, xv.y, xv.z, xv.w };
  float4 o;
  float oa[4];
#pragma unroll
  for (int j = 0; j < 4; j++) {
    float mlp = ((c + j) < dout ? bf2f(mv[j]) : 0.f) + xa[j];
    float att = ((1024 + c + j) < dout ? bf2f(av[j]) : 0.f) + xa[j];
    oa[j] = att + p * mlp;
  }
  o.x = oa[0]; o.y = oa[1]; o.z = oa[2]; o.w = oa[3];
  *(float4*)(out + (size_t)t * 1024 + c) = o;
}

extern "C" void kernel_launch(void* const* d_in, const int* in_sizes, int n_in,
                              void* d_out, int out_size, void* d_ws, size_t ws_size,
                              hipStream_t stream) {
  const float* x        = (const float*)d_in[0];
  const float* probs    = (const float*)d_in[1];
  const float* we       = (const float*)d_in[2];
  const float* mlp_bias = (const float*)d_in[3];
  const float* wc       = (const float*)d_in[4];
  const float* cbias    = (const float*)d_in[5];
  const float* n1w      = (const float*)d_in[6];
  const float* n1b      = (const float*)d_in[7];
  const float* n2w      = (const float*)d_in[8];
  const float* n2b      = (const float*)d_in[9];
  const int*   emask    = (const int*)d_in[10];
  float* out = (float*)d_out;

  char* ws = (char*)d_ws;
  size_t off = 0;
  auto alloc = [&](size_t bytes) {
    char* p = ws + off;
    off += (bytes + 255) & ~(size_t)255;
    return p;
  };
  unsigned short* we_bf = (unsigned short*)alloc((size_t)EXP_ * DIM_ * 2);
  unsigned short* wc_bf = (unsigned short*)alloc((size_t)OD_ * CD_ * 2);
  unsigned short* xn    = (unsigned short*)alloc((size_t)NT * DIM_ * 2);  // reused as vrm
  unsigned short* qb    = (unsigned short*)alloc((size_t)NT * DIM_ * 2);
  unsigned short* kv    = (unsigned short*)alloc((size_t)NT * OD_ * 2);   // reused as cy
  unsigned short* kb    = (unsigned short*)alloc((size_t)NT * DIM_ * 2);
  unsigned short* vt    = (unsigned short*)alloc((size_t)NT * DIM_ * 2);
  unsigned short* cc    = (unsigned short*)alloc((size_t)NT * CD_ * 2);
  unsigned short* vrm = xn;
  unsigned short* cy  = kv;
  if (off > ws_size) return;  // insufficient workspace -> visible failure, no OOB

  // allow 128 KiB dynamic LDS for the 8-phase GEMMs (host-side state, not captured)
  hipFuncSetAttribute((const void*)gemm8p<1, 1024, 28>,
                      hipFuncAttributeMaxDynamicSharedMemorySize, 131072);
  hipFuncSetAttribute((const void*)gemm8p<2, 5120, 8>,
                      hipFuncAttributeMaxDynamicSharedMemorySize, 131072);

  cvt_bf16<<<7168, 256, 0, stream>>>(we, we_bf, EXP_ * DIM_);
  cvt_bf16<<<10240, 256, 0, stream>>>(wc, wc_bf, OD_ * CD_);
  ln1_kernel<<<2048, 256, 0, stream>>>(x, n1w, n1b, emask, xn);
  gemm8p<1, 1024, 28><<<896, 512, 131072, stream>>>(xn, we_bf, mlp_bias, qb, kv, cc);
  ln2_kernel<<<2048, 256, 0, stream>>>(kv, n2w, n2b, kb, vrm);
  transpose_v<<<2048, 256, 0, stream>>>(vrm, vt);
  attn_kernel<<<4096, 64, 0, stream>>>(qb, kb, vt, cc);
  gemm8p<2, 5120, 8><<<256, 512, 131072, stream>>>(cc, wc_bf, cbias, cy, nullptr, nullptr);
  final_epi<<<8192, 256, 0, stream>>>(cy, x, probs, emask, out);
}